// Round 9
// baseline (159.471 us; speedup 1.0000x reference)
//
#include <hip/hip_runtime.h>

#define NCH 64
#define LAG 5
#define H0 32
#define H1 32
#define TIN 2048
#define TOUT 2044
#define NBATCH 16

#define XSTRIDE 72   // ushorts per staged X row (144 B = 128 data + 16 pad)

typedef __attribute__((ext_vector_type(8))) short short8;    // 8 bf16 (4 VGPRs)
typedef __attribute__((ext_vector_type(4))) short short4v;   // 4 bf16 (2 VGPRs)
typedef __attribute__((ext_vector_type(4))) float f32x4;

__device__ __forceinline__ unsigned short f2bf(float f) {
    unsigned u = __float_as_uint(f);
    u += 0x7fffu + ((u >> 16) & 1u);     // RNE
    return (unsigned short)(u >> 16);
}

// ReLU + round-half-up bf16 pack: inputs are >= 0 after fmax, so u+0x8000
// then hi16 is round-half-up (max err 0.5 ulp, same bound as RNE).
// One v_perm_b32 extracts both hi16s: dst = [ua.b2, ua.b3, ub.b2, ub.b3].
__device__ __forceinline__ unsigned pack2bf_relu(float a, float b) {
    unsigned ua = __float_as_uint(fmaxf(a, 0.0f)) + 0x8000u;
    unsigned ub = __float_as_uint(fmaxf(b, 0.0f)) + 0x8000u;
    return __builtin_amdgcn_perm(ub, ua, 0x07060302u);   // src0=ub (idx 4-7), src1=ua (idx 0-3)
}

__device__ __forceinline__ short4v pack4bf_relu(const f32x4& v) {
    union { short4v s; unsigned u[2]; } cv;
    cv.u[0] = pack2bf_relu(v[0], v[1]);
    cv.u[1] = pack2bf_relu(v[2], v[3]);
    return cv.s;
}

// ---- fused prep: X -> padded bf16 image | W0 repack | W1 | W2 ----
// X branch: 64 B/thread (4x float4 read, 2x 16-B contiguous store) -> 512 blocks.
__global__ __launch_bounds__(256) void prep_all(
    const float* __restrict__ X,  unsigned short* __restrict__ Xpad,
    const float* __restrict__ W0, unsigned short* __restrict__ W0b,
    const float* __restrict__ W1, unsigned short* __restrict__ W1b,
    const float* __restrict__ W2, unsigned short* __restrict__ W2b)
{
    const int bx = blockIdx.x;
    if (bx < 512) {
        int id  = bx * 256 + threadIdx.x;      // 131,072 ids; each = 4 float4-groups
        int row = id >> 2, s4 = id & 3;
        const float4* src = (const float4*)(X + (size_t)id * 16);
        unsigned long long v[4];
        #pragma unroll
        for (int k = 0; k < 4; ++k) {
            float4 x = src[k];
            v[k] = (unsigned long long)f2bf(x.x)
                 | ((unsigned long long)f2bf(x.y) << 16)
                 | ((unsigned long long)f2bf(x.z) << 32)
                 | ((unsigned long long)f2bf(x.w) << 48);
        }
        unsigned long long* dst = (unsigned long long*)(Xpad + (size_t)row * XSTRIDE + s4 * 16);
        dst[0] = v[0]; dst[1] = v[1]; dst[2] = v[2]; dst[3] = v[3];
    } else if (bx < 1024) {
        int j = (bx - 512) * 256 + threadIdx.x;   // 131072 = 64n*32h*64c
        int nh = j >> 6, c = j & 63;
        const float* src = W0 + (size_t)j * LAG;
        unsigned short* dst = W0b + nh * 320 + c;
        #pragma unroll
        for (int l = 0; l < LAG; ++l) dst[l * 64] = f2bf(src[l]);
    } else if (bx < 1056) {
        int i = ((bx - 1024) * 256 + threadIdx.x) * 8;
        float4 a = *(const float4*)(W1 + i);
        float4 b = *(const float4*)(W1 + i + 4);
        unsigned long long v0 = (unsigned long long)f2bf(a.x)
                              | ((unsigned long long)f2bf(a.y) << 16)
                              | ((unsigned long long)f2bf(a.z) << 32)
                              | ((unsigned long long)f2bf(a.w) << 48);
        unsigned long long v1 = (unsigned long long)f2bf(b.x)
                              | ((unsigned long long)f2bf(b.y) << 16)
                              | ((unsigned long long)f2bf(b.z) << 32)
                              | ((unsigned long long)f2bf(b.w) << 48);
        *(unsigned long long*)(W1b + i)     = v0;
        *(unsigned long long*)(W1b + i + 4) = v1;
    } else {
        int i = threadIdx.x * 8;
        float4 a = *(const float4*)(W2 + i);
        float4 b = *(const float4*)(W2 + i + 4);
        unsigned long long v0 = (unsigned long long)f2bf(a.x)
                              | ((unsigned long long)f2bf(a.y) << 16)
                              | ((unsigned long long)f2bf(a.z) << 32)
                              | ((unsigned long long)f2bf(a.w) << 48);
        unsigned long long v1 = (unsigned long long)f2bf(b.x)
                              | ((unsigned long long)f2bf(b.y) << 16)
                              | ((unsigned long long)f2bf(b.z) << 32)
                              | ((unsigned long long)f2bf(b.w) << 48);
        *(unsigned long long*)(W2b + i)     = v0;
        *(unsigned long long*)(W2b + i + 4) = v1;
    }
}

// ---- main: block = 256-pos tile x 4 nets; wave = net; X read from L2 ----
// R8 post-mortem: 3 consecutive occupancy-nulls -> reg bracket unreachable
// (total ~ arch + ~112 AGPR ~= 180 > 168 while B0 resident). Accept 2
// waves/SIMD; attack the largest pipe term instead. Per-CU per chunk-round:
// LDS ~1920 cyc (8 waves x 20 ds_read_b128, 4x cross-wave duplication of X),
// VALU ~640/SIMD, matrix ~390/SIMD. Fix: read Xf DIRECTLY from L2 (Xpad is
// 4.7 MB, L2-resident; VMEM pipe nearly idle at 5.5% HBM). Addressing:
// uniform SGPR base + one per-lane voff (+4608/chunk); all 20 ks offsets
// fold into the 13-bit global_load immediate (max 2944). Each 64-B line
// serves 4 quads of one l15 -> no overfetch; ~5 KB L1 footprint per wave.
// xs (37.9 KB), the DMA loop and its barrier drain are deleted; LDS = 13 KB.
__global__ __launch_bounds__(256, 3) void mlp_mfma(
    const unsigned short* __restrict__ Xpad,
    const unsigned short* __restrict__ W0b,
    const unsigned short* __restrict__ W1b,
    const unsigned short* __restrict__ W2b,
    const float* __restrict__ b0, const float* __restrict__ b1,
    const float* __restrict__ b2, float* __restrict__ out)
{
    __shared__ __align__(8)  unsigned short yt[256][4];          //  2,048 B (bf16)
    __shared__ __align__(16) float bl[256];                      //  1,024 B: [0..127]=b0, [128..255]=b1
    __shared__ __align__(8)  unsigned at[256 * 10];              // 10,240 B: per-lane A1 (40-B stride)

    const int tileid = blockIdx.x;
    const int ng     = blockIdx.y;
    const int b      = tileid >> 3;
    const int t0     = (tileid & 7) * 256;
    const int tid    = threadIdx.x;
    const int wave   = tid >> 6;
    const int lane   = tid & 63;
    const int quad   = lane >> 4;
    const int l15    = lane & 15;

    // ---- stage biases: b0/b1 for this block's 4 nets -> LDS (1 KB) ----
    if (tid < 128)       bl[tid]       = b0[ng * 128 + tid];         // bl[w*32+h]
    else                 bl[tid]       = b1[ng * 128 + (tid - 128)]; // bl[128+w*32+o]

    // ---- per-wave net: weight fragments (pre-repacked bf16), loaded once ----
    const int n = ng * 4 + wave;
    short8 B0[10][2];
    const unsigned short* wp0 = W0b + (n * H0 + l15) * (NCH * LAG) + quad * 8;
    #pragma unroll
    for (int ks = 0; ks < 10; ++ks) {
        B0[ks][0] = *(const short8*)(wp0 + ks * 32);
        B0[ks][1] = *(const short8*)(wp0 + 16 * (NCH * LAG) + ks * 32);
    }
    // A1 fragments: global -> LDS per-lane record (dead in regs after this)
    {
        char* rec = (char*)at + tid * 40;
        #pragma unroll
        for (int of = 0; of < 2; ++of)
            #pragma unroll
            for (int kf = 0; kf < 2; ++kf) {
                short4v f = *(const short4v*)(W1b + (n * H1 + of * 16 + l15) * H0 + kf * 16 + quad * 4);
                *(short4v*)(rec + (of * 2 + kf) * 8) = f;
            }
    }
    short4v A2[2];
    #pragma unroll
    for (int kf = 0; kf < 2; ++kf)
        A2[kf] = *(const short4v*)(W2b + n * H1 + kf * 16 + quad * 4);
    const float b2s = __uint_as_float(__builtin_amdgcn_readfirstlane(__float_as_uint(b2[n])));

    __syncthreads();   // bias/A1 LDS stores visible to own wave's later reads

    const float* bp = bl + wave * 32 + quad * 4;   // per-lane bias base (broadcast in 16-lane groups)
    const char*  ap = (const char*)at + tid * 40;  // per-lane A1 record

    // X source: uniform base (SGPR) + per-lane 32-bit voffset, ks offsets as imms.
    const char* xb = (const char*)(Xpad + (size_t)(b * TIN + t0) * XSTRIDE);
    unsigned voff = (unsigned)(l15 * 144 + quad * 16);   // row l15, quad segment (chunk 0)

    #pragma unroll 1
    for (int chunk = 0; chunk < 8; ++chunk) {
        // laundered offset: prevents LICM from hoisting the per-chunk bias/A1
        // ds_reads into loop-invariant registers
        unsigned loff = 0;
        asm volatile("" : "+v"(loff));

        // bias reads: 4x ds_read_b128, broadcast within quads, conflict-free
        f32x4 b0v[2], b1v[2];
        b0v[0] = *(const f32x4*)(bp + loff);
        b0v[1] = *(const f32x4*)(bp + loff + 16);
        b1v[0] = *(const f32x4*)(bp + loff + 128);
        b1v[1] = *(const f32x4*)(bp + loff + 144);

        const char* xp = xb + voff;   // mf0 row; mf1 = +2304 (16 rows)

        // ---- layer 0 (transposed): acc[mf][nf] = C[row=h][col=pos] ----
        f32x4 acc[2][2];
        acc[0][0] = b0v[0]; acc[0][1] = b0v[1];
        acc[1][0] = b0v[0]; acc[1][1] = b0v[1];
        __builtin_amdgcn_s_setprio(1);
        #pragma unroll
        for (int ks = 0; ks < 10; ++ks) {
            const int xoff = (ks >> 1) * 144 + (ks & 1) * 64;   // byte imm, max 640
            short8 Xf0 = *(const short8*)(xp + xoff);           // L2 hit, line-shared by 4 quads
            short8 Xf1 = *(const short8*)(xp + 2304 + xoff);
            acc[0][0] = __builtin_amdgcn_mfma_f32_16x16x32_bf16(B0[ks][0], Xf0, acc[0][0], 0, 0, 0);
            acc[0][1] = __builtin_amdgcn_mfma_f32_16x16x32_bf16(B0[ks][1], Xf0, acc[0][1], 0, 0, 0);
            acc[1][0] = __builtin_amdgcn_mfma_f32_16x16x32_bf16(B0[ks][0], Xf1, acc[1][0], 0, 0, 0);
            acc[1][1] = __builtin_amdgcn_mfma_f32_16x16x32_bf16(B0[ks][1], Xf1, acc[1][1], 0, 0, 0);
        }
        __builtin_amdgcn_s_setprio(0);
        voff += 4608;   // 32 rows

        // A1 fragments for this chunk: 4x ds_read_b64 (4-way max, tail-side)
        short4v A1r[4];
        A1r[0] = *(const short4v*)(ap + loff);
        A1r[1] = *(const short4v*)(ap + loff + 8);
        A1r[2] = *(const short4v*)(ap + loff + 16);
        A1r[3] = *(const short4v*)(ap + loff + 24);

        // ---- layers 1+2: register-only ----
        #pragma unroll
        for (int mf = 0; mf < 2; ++mf) {
            short4v Bh0 = pack4bf_relu(acc[mf][0]);   // h 0..15
            short4v Bh1 = pack4bf_relu(acc[mf][1]);   // h 16..31

            f32x4 D1[2] = { b1v[0], b1v[1] };
            D1[0] = __builtin_amdgcn_mfma_f32_16x16x16bf16_1k(A1r[0], Bh0, D1[0], 0, 0, 0);
            D1[0] = __builtin_amdgcn_mfma_f32_16x16x16bf16_1k(A1r[1], Bh1, D1[0], 0, 0, 0);
            D1[1] = __builtin_amdgcn_mfma_f32_16x16x16bf16_1k(A1r[2], Bh0, D1[1], 0, 0, 0);
            D1[1] = __builtin_amdgcn_mfma_f32_16x16x16bf16_1k(A1r[3], Bh1, D1[1], 0, 0, 0);

            short4v Bg0 = pack4bf_relu(D1[0]);        // o 0..15
            short4v Bg1 = pack4bf_relu(D1[1]);        // o 16..31

            f32x4 D2 = (f32x4){ b2s, b2s, b2s, b2s };
            D2 = __builtin_amdgcn_mfma_f32_16x16x16bf16_1k(A2[0], Bg0, D2, 0, 0, 0);
            D2 = __builtin_amdgcn_mfma_f32_16x16x16bf16_1k(A2[1], Bg1, D2, 0, 0, 0);

            if (quad == 0)
                yt[chunk * 32 + mf * 16 + l15][wave] = f2bf(D2[0]);
        }
    }
    __syncthreads();

    // ---- coalesced output: bf16 yt -> float4 per thread ----
    int t = t0 + tid;
    if (t < TOUT) {
        ushort4 v = *(const ushort4*)yt[tid];
        float4 o;
        o.x = __uint_as_float((unsigned)v.x << 16);
        o.y = __uint_as_float((unsigned)v.y << 16);
        o.z = __uint_as_float((unsigned)v.z << 16);
        o.w = __uint_as_float((unsigned)v.w << 16);
        *(float4*)&out[((size_t)(b * TOUT + t)) * NCH + ng * 4] = o;
    }
}

extern "C" void kernel_launch(void* const* d_in, const int* in_sizes, int n_in,
                              void* d_out, int out_size, void* d_ws, size_t ws_size,
                              hipStream_t stream)
{
    const float* X  = (const float*)d_in[0];
    const float* W0 = (const float*)d_in[1];
    const float* b0 = (const float*)d_in[2];
    const float* W1 = (const float*)d_in[3];
    const float* b1 = (const float*)d_in[4];
    const float* W2 = (const float*)d_in[5];
    const float* b2 = (const float*)d_in[6];
    float* out = (float*)d_out;

    // ws layout: Xpad 4,718,592 B (+8,192 cushion for tail over-read), then weights
    unsigned short* Xpad = (unsigned short*)d_ws;
    unsigned short* W0b  = (unsigned short*)((char*)d_ws + 4726784);   // 1,310,720 B
    unsigned short* W1b  = (unsigned short*)((char*)d_ws + 6037504);   //   131,072 B
    unsigned short* W2b  = (unsigned short*)((char*)d_ws + 6168576);   //     4,096 B

    prep_all<<<1057, 256, 0, stream>>>(X, Xpad, W0, W0b, W1, W1b, W2, W2b);
    mlp_mfma<<<dim3(128, 16), 256, 0, stream>>>(Xpad, W0b, W1b, W2b, b0, b1, b2, out);
}

// Round 10
// 135.738 us; speedup vs baseline: 1.1748x; 1.1748x over previous
//
#include <hip/hip_runtime.h>

#define NCH 64
#define LAG 5
#define H0 32
#define H1 32
#define TIN 2048
#define TOUT 2044
#define NBATCH 16

#define XSTRIDE 72   // ushorts per staged X row (144 B = 128 data + 16 pad)

typedef __attribute__((ext_vector_type(8))) short short8;    // 8 bf16 (4 VGPRs)
typedef __attribute__((ext_vector_type(4))) short short4v;   // 4 bf16 (2 VGPRs)
typedef __attribute__((ext_vector_type(4))) float f32x4;

__device__ __forceinline__ unsigned short f2bf(float f) {
    unsigned u = __float_as_uint(f);
    u += 0x7fffu + ((u >> 16) & 1u);     // RNE
    return (unsigned short)(u >> 16);
}

// ReLU + round-half-up bf16 pack: inputs are >= 0 after fmax, so u+0x8000
// then hi16 is round-half-up (max err 0.5 ulp, same bound as RNE).
// One v_perm_b32 extracts both hi16s: dst = [ua.b2, ua.b3, ub.b2, ub.b3].
__device__ __forceinline__ unsigned pack2bf_relu(float a, float b) {
    unsigned ua = __float_as_uint(fmaxf(a, 0.0f)) + 0x8000u;
    unsigned ub = __float_as_uint(fmaxf(b, 0.0f)) + 0x8000u;
    return __builtin_amdgcn_perm(ub, ua, 0x07060302u);   // src0=ub (idx 4-7), src1=ua (idx 0-3)
}

__device__ __forceinline__ short4v pack4bf_relu(const f32x4& v) {
    union { short4v s; unsigned u[2]; } cv;
    cv.u[0] = pack2bf_relu(v[0], v[1]);
    cv.u[1] = pack2bf_relu(v[2], v[3]);
    return cv.s;
}

// ---- fused prep: X -> padded bf16 image | W0 repack | W1 | W2 ----
// X branch: 64 B/thread (4x float4 read, 2x 16-B contiguous store) -> 512 blocks.
__global__ __launch_bounds__(256) void prep_all(
    const float* __restrict__ X,  unsigned short* __restrict__ Xpad,
    const float* __restrict__ W0, unsigned short* __restrict__ W0b,
    const float* __restrict__ W1, unsigned short* __restrict__ W1b,
    const float* __restrict__ W2, unsigned short* __restrict__ W2b)
{
    const int bx = blockIdx.x;
    if (bx < 512) {
        int id  = bx * 256 + threadIdx.x;      // 131,072 ids; each = 4 float4-groups
        int row = id >> 2, s4 = id & 3;
        const float4* src = (const float4*)(X + (size_t)id * 16);
        unsigned long long v[4];
        #pragma unroll
        for (int k = 0; k < 4; ++k) {
            float4 x = src[k];
            v[k] = (unsigned long long)f2bf(x.x)
                 | ((unsigned long long)f2bf(x.y) << 16)
                 | ((unsigned long long)f2bf(x.z) << 32)
                 | ((unsigned long long)f2bf(x.w) << 48);
        }
        unsigned long long* dst = (unsigned long long*)(Xpad + (size_t)row * XSTRIDE + s4 * 16);
        dst[0] = v[0]; dst[1] = v[1]; dst[2] = v[2]; dst[3] = v[3];
    } else if (bx < 1024) {
        int j = (bx - 512) * 256 + threadIdx.x;   // 131072 = 64n*32h*64c
        int nh = j >> 6, c = j & 63;
        const float* src = W0 + (size_t)j * LAG;
        unsigned short* dst = W0b + nh * 320 + c;
        #pragma unroll
        for (int l = 0; l < LAG; ++l) dst[l * 64] = f2bf(src[l]);
    } else if (bx < 1056) {
        int i = ((bx - 1024) * 256 + threadIdx.x) * 8;
        float4 a = *(const float4*)(W1 + i);
        float4 b = *(const float4*)(W1 + i + 4);
        unsigned long long v0 = (unsigned long long)f2bf(a.x)
                              | ((unsigned long long)f2bf(a.y) << 16)
                              | ((unsigned long long)f2bf(a.z) << 32)
                              | ((unsigned long long)f2bf(a.w) << 48);
        unsigned long long v1 = (unsigned long long)f2bf(b.x)
                              | ((unsigned long long)f2bf(b.y) << 16)
                              | ((unsigned long long)f2bf(b.z) << 32)
                              | ((unsigned long long)f2bf(b.w) << 48);
        *(unsigned long long*)(W1b + i)     = v0;
        *(unsigned long long*)(W1b + i + 4) = v1;
    } else {
        int i = threadIdx.x * 8;
        float4 a = *(const float4*)(W2 + i);
        float4 b = *(const float4*)(W2 + i + 4);
        unsigned long long v0 = (unsigned long long)f2bf(a.x)
                              | ((unsigned long long)f2bf(a.y) << 16)
                              | ((unsigned long long)f2bf(a.z) << 32)
                              | ((unsigned long long)f2bf(a.w) << 48);
        unsigned long long v1 = (unsigned long long)f2bf(b.x)
                              | ((unsigned long long)f2bf(b.y) << 16)
                              | ((unsigned long long)f2bf(b.z) << 32)
                              | ((unsigned long long)f2bf(b.w) << 48);
        *(unsigned long long*)(W2b + i)     = v0;
        *(unsigned long long*)(W2b + i + 4) = v1;
    }
}

// ---- main: block = 256-pos tile x 4 nets; wave = net; hybrid X fetch ----
// R9 post-mortem: pure L2-X (just-in-time loads) = 95us with ZERO bank
// conflicts -- the stall is just-in-time operand latency, not pipe choice.
// Fix: fetch a chunk AHEAD. mf0's 10 X-fragments are prefetched from L2 into
// 40 VGPRs one full chunk early (~1500 cyc of compute covers ~300 cyc vmcnt);
// mf1 stays on LDS ds_reads. Per-wave LDS reads/chunk 20->10; lgkm chains
// halve. Budget: 2-wave bracket has ~70 free VGPRs (R5/R8: anything 170-256
// unified = 2 waves/SIMD). launch_bounds(256,2) so regalloc uses the full
// budget without spilling. Chunk-8 prefetch overruns the tile by <2.8 KB --
// inside Xpad's 8 KB cushion; values never consumed.
__global__ __launch_bounds__(256, 2) void mlp_mfma(
    const unsigned short* __restrict__ Xpad,
    const unsigned short* __restrict__ W0b,
    const unsigned short* __restrict__ W1b,
    const unsigned short* __restrict__ W2b,
    const float* __restrict__ b0, const float* __restrict__ b1,
    const float* __restrict__ b2, float* __restrict__ out)
{
    __shared__ __align__(16) unsigned short xs[37 * 512];        // 37,888 B
    __shared__ __align__(8)  unsigned short yt[256][4];          //  2,048 B (bf16)
    __shared__ __align__(16) float bl[256];                      //  1,024 B: [0..127]=b0, [128..255]=b1
    __shared__ __align__(8)  unsigned at[256 * 10];              // 10,240 B: per-lane A1 (40-B stride)

    const int tileid = blockIdx.x;
    const int ng     = blockIdx.y;
    const int b      = tileid >> 3;
    const int t0     = (tileid & 7) * 256;
    const int tid    = threadIdx.x;
    const int wave   = tid >> 6;
    const int lane   = tid & 63;
    const int quad   = lane >> 4;
    const int l15    = lane & 15;

    // ---- stage X tile: direct global->LDS DMA, 1 KB per instruction ----
    {
        const char* srcb = (const char*)(Xpad + (size_t)(b * TIN + t0) * XSTRIDE);
        #pragma unroll 1
        for (int i = wave; i < 37; i += 4) {
            __builtin_amdgcn_global_load_lds(
                (const __attribute__((address_space(1))) unsigned int*)(srcb + i * 1024 + lane * 16),
                (__attribute__((address_space(3))) unsigned int*)((char*)xs + i * 1024),
                16, 0, 0);
        }
    }

    // ---- stage biases: b0/b1 for this block's 4 nets -> LDS (1 KB) ----
    if (tid < 128)       bl[tid]       = b0[ng * 128 + tid];         // bl[w*32+h]
    else                 bl[tid]       = b1[ng * 128 + (tid - 128)]; // bl[128+w*32+o]

    // ---- per-wave net: weight fragments (pre-repacked bf16), loaded once ----
    const int n = ng * 4 + wave;
    short8 B0[10][2];
    const unsigned short* wp0 = W0b + (n * H0 + l15) * (NCH * LAG) + quad * 8;
    #pragma unroll
    for (int ks = 0; ks < 10; ++ks) {
        B0[ks][0] = *(const short8*)(wp0 + ks * 32);
        B0[ks][1] = *(const short8*)(wp0 + 16 * (NCH * LAG) + ks * 32);
    }
    // A1 fragments: global -> LDS per-lane record (dead in regs after this)
    {
        char* rec = (char*)at + tid * 40;
        #pragma unroll
        for (int of = 0; of < 2; ++of)
            #pragma unroll
            for (int kf = 0; kf < 2; ++kf) {
                short4v f = *(const short4v*)(W1b + (n * H1 + of * 16 + l15) * H0 + kf * 16 + quad * 4);
                *(short4v*)(rec + (of * 2 + kf) * 8) = f;
            }
    }
    short4v A2[2];
    #pragma unroll
    for (int kf = 0; kf < 2; ++kf)
        A2[kf] = *(const short4v*)(W2b + n * H1 + kf * 16 + quad * 4);
    const float b2s = __uint_as_float(__builtin_amdgcn_readfirstlane(__float_as_uint(b2[n])));

    // ---- prefetch chunk 0's mf0 X-fragments from L2 (latency hidden by barrier) ----
    const char* xg = (const char*)(Xpad + (size_t)(b * TIN + t0) * XSTRIDE)
                   + (l15 * 144 + quad * 16);
    short8 P[10];
    #pragma unroll
    for (int ks = 0; ks < 10; ++ks)
        P[ks] = *(const short8*)(xg + (ks >> 1) * 144 + (ks & 1) * 64);

    __syncthreads();   // drains global_load_lds (vmcnt) + weight/bias/A1 stores

    const float* bp = bl + wave * 32 + quad * 4;   // per-lane bias base (broadcast in 16-lane groups)
    const char*  ap = (const char*)at + tid * 40;  // per-lane A1 record

    #pragma unroll 1
    for (int chunk = 0; chunk < 8; ++chunk) {
        // laundered offset: prevents LICM from hoisting the per-chunk bias/A1
        // ds_reads into loop-invariant registers
        unsigned loff = 0;
        asm volatile("" : "+v"(loff));

        const int rowoff1 = (chunk * 32 + 16 + l15) * XSTRIDE + quad * 8;   // mf1 rows (LDS)

        // bias reads: 4x ds_read_b128, broadcast within quads, conflict-free
        f32x4 b0v[2], b1v[2];
        b0v[0] = *(const f32x4*)(bp + loff);
        b0v[1] = *(const f32x4*)(bp + loff + 16);
        b1v[0] = *(const f32x4*)(bp + loff + 128);
        b1v[1] = *(const f32x4*)(bp + loff + 144);

        // ---- layer 0 (transposed): acc[mf][nf] = C[row=h][col=pos] ----
        f32x4 acc[2][2];
        acc[0][0] = b0v[0]; acc[0][1] = b0v[1];
        acc[1][0] = b0v[0]; acc[1][1] = b0v[1];

        // mf0: operands already in registers (prefetched last chunk; vmcnt long satisfied)
        __builtin_amdgcn_s_setprio(1);
        #pragma unroll
        for (int ks = 0; ks < 10; ++ks) {
            acc[0][0] = __builtin_amdgcn_mfma_f32_16x16x32_bf16(B0[ks][0], P[ks], acc[0][0], 0, 0, 0);
            acc[0][1] = __builtin_amdgcn_mfma_f32_16x16x32_bf16(B0[ks][1], P[ks], acc[0][1], 0, 0, 0);
        }
        __builtin_amdgcn_s_setprio(0);

        // issue next chunk's mf0 prefetch (consumed ~1500 cyc from now)
        {
            const char* xn = xg + (chunk + 1) * 4608;
            #pragma unroll
            for (int ks = 0; ks < 10; ++ks)
                P[ks] = *(const short8*)(xn + (ks >> 1) * 144 + (ks & 1) * 64);
        }

        // mf1: from LDS
        __builtin_amdgcn_s_setprio(1);
        #pragma unroll
        for (int ks = 0; ks < 10; ++ks) {
            const int xoff = (ks >> 1) * XSTRIDE + (ks & 1) * 32;
            short8 Xf1 = *(const short8*)&xs[rowoff1 + xoff];
            acc[1][0] = __builtin_amdgcn_mfma_f32_16x16x32_bf16(B0[ks][0], Xf1, acc[1][0], 0, 0, 0);
            acc[1][1] = __builtin_amdgcn_mfma_f32_16x16x32_bf16(B0[ks][1], Xf1, acc[1][1], 0, 0, 0);
        }
        __builtin_amdgcn_s_setprio(0);

        // A1 fragments for this chunk: 4x ds_read_b64 (4-way max, tail-side)
        short4v A1r[4];
        A1r[0] = *(const short4v*)(ap + loff);
        A1r[1] = *(const short4v*)(ap + loff + 8);
        A1r[2] = *(const short4v*)(ap + loff + 16);
        A1r[3] = *(const short4v*)(ap + loff + 24);

        // ---- layers 1+2: register-only ----
        #pragma unroll
        for (int mf = 0; mf < 2; ++mf) {
            short4v Bh0 = pack4bf_relu(acc[mf][0]);   // h 0..15
            short4v Bh1 = pack4bf_relu(acc[mf][1]);   // h 16..31

            f32x4 D1[2] = { b1v[0], b1v[1] };
            D1[0] = __builtin_amdgcn_mfma_f32_16x16x16bf16_1k(A1r[0], Bh0, D1[0], 0, 0, 0);
            D1[0] = __builtin_amdgcn_mfma_f32_16x16x16bf16_1k(A1r[1], Bh1, D1[0], 0, 0, 0);
            D1[1] = __builtin_amdgcn_mfma_f32_16x16x16bf16_1k(A1r[2], Bh0, D1[1], 0, 0, 0);
            D1[1] = __builtin_amdgcn_mfma_f32_16x16x16bf16_1k(A1r[3], Bh1, D1[1], 0, 0, 0);

            short4v Bg0 = pack4bf_relu(D1[0]);        // o 0..15
            short4v Bg1 = pack4bf_relu(D1[1]);        // o 16..31

            f32x4 D2 = (f32x4){ b2s, b2s, b2s, b2s };
            D2 = __builtin_amdgcn_mfma_f32_16x16x16bf16_1k(A2[0], Bg0, D2, 0, 0, 0);
            D2 = __builtin_amdgcn_mfma_f32_16x16x16bf16_1k(A2[1], Bg1, D2, 0, 0, 0);

            if (quad == 0)
                yt[chunk * 32 + mf * 16 + l15][wave] = f2bf(D2[0]);
        }
    }
    __syncthreads();

    // ---- coalesced output: bf16 yt -> float4 per thread ----
    int t = t0 + tid;
    if (t < TOUT) {
        ushort4 v = *(const ushort4*)yt[tid];
        float4 o;
        o.x = __uint_as_float((unsigned)v.x << 16);
        o.y = __uint_as_float((unsigned)v.y << 16);
        o.z = __uint_as_float((unsigned)v.z << 16);
        o.w = __uint_as_float((unsigned)v.w << 16);
        *(float4*)&out[((size_t)(b * TOUT + t)) * NCH + ng * 4] = o;
    }
}

extern "C" void kernel_launch(void* const* d_in, const int* in_sizes, int n_in,
                              void* d_out, int out_size, void* d_ws, size_t ws_size,
                              hipStream_t stream)
{
    const float* X  = (const float*)d_in[0];
    const float* W0 = (const float*)d_in[1];
    const float* b0 = (const float*)d_in[2];
    const float* W1 = (const float*)d_in[3];
    const float* b1 = (const float*)d_in[4];
    const float* W2 = (const float*)d_in[5];
    const float* b2 = (const float*)d_in[6];
    float* out = (float*)d_out;

    // ws layout: Xpad 4,718,592 B (+8,192 cushion for tail over-read), then weights
    unsigned short* Xpad = (unsigned short*)d_ws;
    unsigned short* W0b  = (unsigned short*)((char*)d_ws + 4726784);   // 1,310,720 B
    unsigned short* W1b  = (unsigned short*)((char*)d_ws + 6037504);   //   131,072 B
    unsigned short* W2b  = (unsigned short*)((char*)d_ws + 6168576);   //     4,096 B

    prep_all<<<1057, 256, 0, stream>>>(X, Xpad, W0, W0b, W1, W1b, W2, W2b);
    mlp_mfma<<<dim3(128, 16), 256, 0, stream>>>(Xpad, W0b, W1b, W2b, b0, b1, b2, out);
}

// Round 11
// 129.935 us; speedup vs baseline: 1.2273x; 1.0447x over previous
//
#include <hip/hip_runtime.h>

#define NCH 64
#define LAG 5
#define H0 32
#define H1 32
#define TIN 2048
#define TOUT 2044
#define NBATCH 16

#define XSTRIDE 72   // ushorts per staged X row (144 B = 128 data + 16 pad)

typedef __attribute__((ext_vector_type(8))) short short8;    // 8 bf16 (4 VGPRs)
typedef __attribute__((ext_vector_type(4))) short short4v;   // 4 bf16 (2 VGPRs)
typedef __attribute__((ext_vector_type(4))) float f32x4;

__device__ __forceinline__ unsigned short f2bf(float f) {
    unsigned u = __float_as_uint(f);
    u += 0x7fffu + ((u >> 16) & 1u);     // RNE
    return (unsigned short)(u >> 16);
}

// ReLU + round-half-up bf16 pack: inputs are >= 0 after fmax, so u+0x8000
// then hi16 is round-half-up (max err 0.5 ulp, same bound as RNE).
// One v_perm_b32 extracts both hi16s: dst = [ua.b2, ua.b3, ub.b2, ub.b3].
__device__ __forceinline__ unsigned pack2bf_relu(float a, float b) {
    unsigned ua = __float_as_uint(fmaxf(a, 0.0f)) + 0x8000u;
    unsigned ub = __float_as_uint(fmaxf(b, 0.0f)) + 0x8000u;
    return __builtin_amdgcn_perm(ub, ua, 0x07060302u);   // src0=ub (idx 4-7), src1=ua (idx 0-3)
}

__device__ __forceinline__ short4v pack4bf_relu(const f32x4& v) {
    union { short4v s; unsigned u[2]; } cv;
    cv.u[0] = pack2bf_relu(v[0], v[1]);
    cv.u[1] = pack2bf_relu(v[2], v[3]);
    return cv.s;
}

// ---- fused prep: X -> padded bf16 image | W0 repack | W1 | W2 ----
// X branch: 64 B/thread (4x float4 read, 2x 16-B contiguous store) -> 512 blocks.
__global__ __launch_bounds__(256) void prep_all(
    const float* __restrict__ X,  unsigned short* __restrict__ Xpad,
    const float* __restrict__ W0, unsigned short* __restrict__ W0b,
    const float* __restrict__ W1, unsigned short* __restrict__ W1b,
    const float* __restrict__ W2, unsigned short* __restrict__ W2b)
{
    const int bx = blockIdx.x;
    if (bx < 512) {
        int id  = bx * 256 + threadIdx.x;      // 131,072 ids; each = 4 float4-groups
        int row = id >> 2, s4 = id & 3;
        const float4* src = (const float4*)(X + (size_t)id * 16);
        unsigned long long v[4];
        #pragma unroll
        for (int k = 0; k < 4; ++k) {
            float4 x = src[k];
            v[k] = (unsigned long long)f2bf(x.x)
                 | ((unsigned long long)f2bf(x.y) << 16)
                 | ((unsigned long long)f2bf(x.z) << 32)
                 | ((unsigned long long)f2bf(x.w) << 48);
        }
        unsigned long long* dst = (unsigned long long*)(Xpad + (size_t)row * XSTRIDE + s4 * 16);
        dst[0] = v[0]; dst[1] = v[1]; dst[2] = v[2]; dst[3] = v[3];
    } else if (bx < 1024) {
        int j = (bx - 512) * 256 + threadIdx.x;   // 131072 = 64n*32h*64c
        int nh = j >> 6, c = j & 63;
        const float* src = W0 + (size_t)j * LAG;
        unsigned short* dst = W0b + nh * 320 + c;
        #pragma unroll
        for (int l = 0; l < LAG; ++l) dst[l * 64] = f2bf(src[l]);
    } else if (bx < 1056) {
        int i = ((bx - 1024) * 256 + threadIdx.x) * 8;
        float4 a = *(const float4*)(W1 + i);
        float4 b = *(const float4*)(W1 + i + 4);
        unsigned long long v0 = (unsigned long long)f2bf(a.x)
                              | ((unsigned long long)f2bf(a.y) << 16)
                              | ((unsigned long long)f2bf(a.z) << 32)
                              | ((unsigned long long)f2bf(a.w) << 48);
        unsigned long long v1 = (unsigned long long)f2bf(b.x)
                              | ((unsigned long long)f2bf(b.y) << 16)
                              | ((unsigned long long)f2bf(b.z) << 32)
                              | ((unsigned long long)f2bf(b.w) << 48);
        *(unsigned long long*)(W1b + i)     = v0;
        *(unsigned long long*)(W1b + i + 4) = v1;
    } else {
        int i = threadIdx.x * 8;
        float4 a = *(const float4*)(W2 + i);
        float4 b = *(const float4*)(W2 + i + 4);
        unsigned long long v0 = (unsigned long long)f2bf(a.x)
                              | ((unsigned long long)f2bf(a.y) << 16)
                              | ((unsigned long long)f2bf(a.z) << 32)
                              | ((unsigned long long)f2bf(a.w) << 48);
        unsigned long long v1 = (unsigned long long)f2bf(b.x)
                              | ((unsigned long long)f2bf(b.y) << 16)
                              | ((unsigned long long)f2bf(b.z) << 32)
                              | ((unsigned long long)f2bf(b.w) << 48);
        *(unsigned long long*)(W2b + i)     = v0;
        *(unsigned long long*)(W2b + i + 4) = v1;
    }
}

// ---- main: block = 256-pos tile x 2 nets x 2 K-halves; wave = (net, kh) ----
// R10 post-mortem: every register-fattening loses occupancy; every latency-
// adding thinning loses worse; R1's bind is B0's 80 regs. K-SPLIT breaks it:
// wave pair (kh=0,1) each computes half of L0's K=320 for the same net ->
// B0 40 regs/wave, X ds_reads/wave halved, tail/wave halved (one mf each).
// Partial sums exchanged through LDS (exA/exB, contiguous 16B/lane) with two
// barriers per chunk. Bias added by kh=0 wave only. LDS 47KB -> 3 blocks/CU;
// regs ~120 -> 3 waves/SIMD -> 12 waves/CU (occ ~37% vs 26%), with shorter
// per-wave serial chains AND ~45% less LDS traffic -- first change moving
// all three binding terms the right way.
__global__ __launch_bounds__(256, 3) void mlp_mfma(
    const unsigned short* __restrict__ Xpad,
    const unsigned short* __restrict__ W0b,
    const unsigned short* __restrict__ W1b,
    const unsigned short* __restrict__ W2b,
    const float* __restrict__ b0, const float* __restrict__ b1,
    const float* __restrict__ b2, float* __restrict__ out)
{
    __shared__ __align__(16) unsigned short xs[37 * 512];        // 37,888 B
    __shared__ __align__(16) f32x4 exA[4][64];                   //  4,096 B (nf0 partials)
    __shared__ __align__(16) f32x4 exB[4][64];                   //  4,096 B (nf1 partials)
    __shared__ __align__(8)  unsigned short yt[256][2];          //  1,024 B (bf16)

    const int tileid = blockIdx.x;
    const int ng     = blockIdx.y;          // 0..31: nets ng*2, ng*2+1
    const int b      = tileid >> 3;
    const int t0     = (tileid & 7) * 256;
    const int tid    = threadIdx.x;
    const int wave   = tid >> 6;
    const int lane   = tid & 63;
    const int quad   = lane >> 4;
    const int l15    = lane & 15;
    const int nl     = wave >> 1;           // net-local 0/1
    const int kh     = wave & 1;            // K-half 0/1

    // ---- stage X tile: direct global->LDS DMA, 1 KB per instruction ----
    {
        const char* srcb = (const char*)(Xpad + (size_t)(b * TIN + t0) * XSTRIDE);
        #pragma unroll 1
        for (int i = wave; i < 37; i += 4) {
            __builtin_amdgcn_global_load_lds(
                (const __attribute__((address_space(1))) unsigned int*)(srcb + i * 1024 + lane * 16),
                (__attribute__((address_space(3))) unsigned int*)((char*)xs + i * 1024),
                16, 0, 0);
        }
    }

    // ---- per-wave: net n, K-half kh. B0 half = 5 frags x 2 nf = 40 VGPRs ----
    const int n = ng * 2 + nl;
    short8 B0h[5][2];
    const unsigned short* wp0 = W0b + (n * H0 + l15) * (NCH * LAG) + quad * 8 + kh * 160;
    #pragma unroll
    for (int j = 0; j < 5; ++j) {
        B0h[j][0] = *(const short8*)(wp0 + j * 32);
        B0h[j][1] = *(const short8*)(wp0 + 16 * (NCH * LAG) + j * 32);
    }
    short4v A1[2][2];
    #pragma unroll
    for (int of = 0; of < 2; ++of)
        #pragma unroll
        for (int kf = 0; kf < 2; ++kf)
            A1[of][kf] = *(const short4v*)(W1b + (n * H1 + of * 16 + l15) * H0 + kf * 16 + quad * 4);
    short4v A2[2];
    #pragma unroll
    for (int kf = 0; kf < 2; ++kf)
        A2[kf] = *(const short4v*)(W2b + n * H1 + kf * 16 + quad * 4);
    f32x4 b0q[2], b1q[2];
    #pragma unroll
    for (int f = 0; f < 2; ++f) b0q[f] = *(const f32x4*)(b0 + (size_t)n * H0 + f * 16 + quad * 4);
    #pragma unroll
    for (int f = 0; f < 2; ++f) b1q[f] = *(const f32x4*)(b1 + (size_t)n * H1 + f * 16 + quad * 4);
    const float b2s = __uint_as_float(__builtin_amdgcn_readfirstlane(__float_as_uint(b2[n])));

    const int kh5 = kh * 5;                 // wave-uniform ks base

    __syncthreads();   // drains global_load_lds (vmcnt) + weight loads

    #pragma unroll 1
    for (int chunk = 0; chunk < 8; ++chunk) {
        const int rowoff0 = (chunk * 32 + l15) * XSTRIDE + quad * 8;        // mf0 pos rows
        const int rowoff1 = rowoff0 + 16 * XSTRIDE;                        // mf1 pos rows

        // ---- L0 partial over this wave's K-half; bias only on kh==0 ----
        f32x4 p00, p01, p10, p11;
        if (kh == 0) { p00 = b0q[0]; p01 = b0q[1]; p10 = b0q[0]; p11 = b0q[1]; }
        else {
            f32x4 z = (f32x4){0.f, 0.f, 0.f, 0.f};
            p00 = z; p01 = z; p10 = z; p11 = z;
        }
        __builtin_amdgcn_s_setprio(1);
        #pragma unroll
        for (int j = 0; j < 5; ++j) {
            const int ks   = kh5 + j;                                      // uniform
            const int xoff = (ks >> 1) * XSTRIDE + (ks & 1) * 32;
            short8 Xf0 = *(const short8*)&xs[rowoff0 + xoff];              // B-op: n=pos
            short8 Xf1 = *(const short8*)&xs[rowoff1 + xoff];
            p00 = __builtin_amdgcn_mfma_f32_16x16x32_bf16(B0h[j][0], Xf0, p00, 0, 0, 0);
            p01 = __builtin_amdgcn_mfma_f32_16x16x32_bf16(B0h[j][1], Xf0, p01, 0, 0, 0);
            p10 = __builtin_amdgcn_mfma_f32_16x16x32_bf16(B0h[j][0], Xf1, p10, 0, 0, 0);
            p11 = __builtin_amdgcn_mfma_f32_16x16x32_bf16(B0h[j][1], Xf1, p11, 0, 0, 0);
        }
        __builtin_amdgcn_s_setprio(0);

        // ---- exchange: give away mf=(1-kh), keep mf=kh (wave-uniform branch) ----
        if (kh == 0) { exA[wave][lane] = p10; exB[wave][lane] = p11; }
        else         { exA[wave][lane] = p00; exB[wave][lane] = p01; }
        __syncthreads();                     // partner's partial visible
        f32x4 rA = exA[wave ^ 1][lane];
        f32x4 rB = exB[wave ^ 1][lane];
        f32x4 fA = (kh == 0 ? p00 : p10) + rA;   // full acc, nf0 (h 0..15)
        f32x4 fB = (kh == 0 ? p01 : p11) + rB;   // full acc, nf1 (h 16..31)

        // ---- layers 1+2 for this wave's mf=kh: register-only ----
        short4v Bh0 = pack4bf_relu(fA);
        short4v Bh1 = pack4bf_relu(fB);

        f32x4 D1[2] = { b1q[0], b1q[1] };
        D1[0] = __builtin_amdgcn_mfma_f32_16x16x16bf16_1k(A1[0][0], Bh0, D1[0], 0, 0, 0);
        D1[0] = __builtin_amdgcn_mfma_f32_16x16x16bf16_1k(A1[0][1], Bh1, D1[0], 0, 0, 0);
        D1[1] = __builtin_amdgcn_mfma_f32_16x16x16bf16_1k(A1[1][0], Bh0, D1[1], 0, 0, 0);
        D1[1] = __builtin_amdgcn_mfma_f32_16x16x16bf16_1k(A1[1][1], Bh1, D1[1], 0, 0, 0);

        short4v Bg0 = pack4bf_relu(D1[0]);        // o 0..15
        short4v Bg1 = pack4bf_relu(D1[1]);        // o 16..31

        f32x4 D2 = (f32x4){ b2s, b2s, b2s, b2s };
        D2 = __builtin_amdgcn_mfma_f32_16x16x16bf16_1k(A2[0], Bg0, D2, 0, 0, 0);
        D2 = __builtin_amdgcn_mfma_f32_16x16x16bf16_1k(A2[1], Bg1, D2, 0, 0, 0);

        if (quad == 0)
            yt[chunk * 32 + kh * 16 + l15][nl] = f2bf(D2[0]);

        __syncthreads();                     // WAR: ex reads done before next write
    }

    // ---- coalesced-ish output: bf16 yt -> float2 per thread ----
    int t = t0 + tid;
    if (t < TOUT) {
        unsigned v = *(const unsigned*)yt[tid];       // 2 bf16
        float2 o;
        o.x = __uint_as_float((v & 0xffffu) << 16);
        o.y = __uint_as_float(v & 0xffff0000u);
        *(float2*)&out[((size_t)(b * TOUT + t)) * NCH + ng * 2] = o;
    }
}

extern "C" void kernel_launch(void* const* d_in, const int* in_sizes, int n_in,
                              void* d_out, int out_size, void* d_ws, size_t ws_size,
                              hipStream_t stream)
{
    const float* X  = (const float*)d_in[0];
    const float* W0 = (const float*)d_in[1];
    const float* b0 = (const float*)d_in[2];
    const float* W1 = (const float*)d_in[3];
    const float* b1 = (const float*)d_in[4];
    const float* W2 = (const float*)d_in[5];
    const float* b2 = (const float*)d_in[6];
    float* out = (float*)d_out;

    // ws layout: Xpad 4,718,592 B (+8,192 cushion for tail over-copy), then weights
    unsigned short* Xpad = (unsigned short*)d_ws;
    unsigned short* W0b  = (unsigned short*)((char*)d_ws + 4726784);   // 1,310,720 B
    unsigned short* W1b  = (unsigned short*)((char*)d_ws + 6037504);   //   131,072 B
    unsigned short* W2b  = (unsigned short*)((char*)d_ws + 6168576);   //     4,096 B

    prep_all<<<1057, 256, 0, stream>>>(X, Xpad, W0, W0b, W1, W1b, W2, W2b);
    mlp_mfma<<<dim3(128, 32), 256, 0, stream>>>(Xpad, W0b, W1b, W2b, b0, b1, b2, out);
}

// Round 12
// 117.441 us; speedup vs baseline: 1.3579x; 1.1064x over previous
//
#include <hip/hip_runtime.h>

#define NCH 64
#define LAG 5
#define H0 32
#define H1 32
#define TIN 2048
#define TOUT 2044
#define NBATCH 16

#define XSTRIDE 72   // ushorts per staged X row (144 B = 128 data + 16 pad)

typedef __attribute__((ext_vector_type(8))) short short8;    // 8 bf16 (4 VGPRs)
typedef __attribute__((ext_vector_type(4))) short short4v;   // 4 bf16 (2 VGPRs)
typedef __attribute__((ext_vector_type(4))) float f32x4;

__device__ __forceinline__ unsigned short f2bf(float f) {
    unsigned u = __float_as_uint(f);
    u += 0x7fffu + ((u >> 16) & 1u);     // RNE
    return (unsigned short)(u >> 16);
}

// ReLU + round-half-up bf16 pack: inputs are >= 0 after fmax, so u+0x8000
// then hi16 is round-half-up (max err 0.5 ulp, same bound as RNE).
// One v_perm_b32 extracts both hi16s: dst = [ua.b2, ua.b3, ub.b2, ub.b3].
__device__ __forceinline__ unsigned pack2bf_relu(float a, float b) {
    unsigned ua = __float_as_uint(fmaxf(a, 0.0f)) + 0x8000u;
    unsigned ub = __float_as_uint(fmaxf(b, 0.0f)) + 0x8000u;
    return __builtin_amdgcn_perm(ub, ua, 0x07060302u);   // src0=ub (idx 4-7), src1=ua (idx 0-3)
}

__device__ __forceinline__ short4v pack4bf_relu(const f32x4& v) {
    union { short4v s; unsigned u[2]; } cv;
    cv.u[0] = pack2bf_relu(v[0], v[1]);
    cv.u[1] = pack2bf_relu(v[2], v[3]);
    return cv.s;
}

// ---- fused prep: X -> padded bf16 image | W0 repack | W1 | W2 ----
// X branch: 64 B/thread (4x float4 read, 2x 16-B contiguous store) -> 512 blocks.
__global__ __launch_bounds__(256) void prep_all(
    const float* __restrict__ X,  unsigned short* __restrict__ Xpad,
    const float* __restrict__ W0, unsigned short* __restrict__ W0b,
    const float* __restrict__ W1, unsigned short* __restrict__ W1b,
    const float* __restrict__ W2, unsigned short* __restrict__ W2b)
{
    const int bx = blockIdx.x;
    if (bx < 512) {
        int id  = bx * 256 + threadIdx.x;      // 131,072 ids; each = 4 float4-groups
        int row = id >> 2, s4 = id & 3;
        const float4* src = (const float4*)(X + (size_t)id * 16);
        unsigned long long v[4];
        #pragma unroll
        for (int k = 0; k < 4; ++k) {
            float4 x = src[k];
            v[k] = (unsigned long long)f2bf(x.x)
                 | ((unsigned long long)f2bf(x.y) << 16)
                 | ((unsigned long long)f2bf(x.z) << 32)
                 | ((unsigned long long)f2bf(x.w) << 48);
        }
        unsigned long long* dst = (unsigned long long*)(Xpad + (size_t)row * XSTRIDE + s4 * 16);
        dst[0] = v[0]; dst[1] = v[1]; dst[2] = v[2]; dst[3] = v[3];
    } else if (bx < 1024) {
        int j = (bx - 512) * 256 + threadIdx.x;   // 131072 = 64n*32h*64c
        int nh = j >> 6, c = j & 63;
        const float* src = W0 + (size_t)j * LAG;
        unsigned short* dst = W0b + nh * 320 + c;
        #pragma unroll
        for (int l = 0; l < LAG; ++l) dst[l * 64] = f2bf(src[l]);
    } else if (bx < 1056) {
        int i = ((bx - 1024) * 256 + threadIdx.x) * 8;
        float4 a = *(const float4*)(W1 + i);
        float4 b = *(const float4*)(W1 + i + 4);
        unsigned long long v0 = (unsigned long long)f2bf(a.x)
                              | ((unsigned long long)f2bf(a.y) << 16)
                              | ((unsigned long long)f2bf(a.z) << 32)
                              | ((unsigned long long)f2bf(a.w) << 48);
        unsigned long long v1 = (unsigned long long)f2bf(b.x)
                              | ((unsigned long long)f2bf(b.y) << 16)
                              | ((unsigned long long)f2bf(b.z) << 32)
                              | ((unsigned long long)f2bf(b.w) << 48);
        *(unsigned long long*)(W1b + i)     = v0;
        *(unsigned long long*)(W1b + i + 4) = v1;
    } else {
        int i = threadIdx.x * 8;
        float4 a = *(const float4*)(W2 + i);
        float4 b = *(const float4*)(W2 + i + 4);
        unsigned long long v0 = (unsigned long long)f2bf(a.x)
                              | ((unsigned long long)f2bf(a.y) << 16)
                              | ((unsigned long long)f2bf(a.z) << 32)
                              | ((unsigned long long)f2bf(a.w) << 48);
        unsigned long long v1 = (unsigned long long)f2bf(b.x)
                              | ((unsigned long long)f2bf(b.y) << 16)
                              | ((unsigned long long)f2bf(b.z) << 32)
                              | ((unsigned long long)f2bf(b.w) << 48);
        *(unsigned long long*)(W2b + i)     = v0;
        *(unsigned long long*)(W2b + i + 4) = v1;
    }
}

// ---- main: block = 256-pos tile x 4 nets; wave = net; register-only L1/L2 ----
// R11 post-mortem: LDS is NOT binding (aux-read nulls R6/R8); no pipe >50%;
// occupancy pinned at 2 waves/SIMD by the ~180-unified-reg floor. Remaining
// theory: co-resident waves run IDENTICAL streams from a common barrier, so
// serial tails align and the matrix pipe idles in unison. Fix (zero-cost):
// rotate each wave's chunk order -- chunk = (ci + phase) & 7 with
// phase = wave*2 + ((tileid^ng)&1). Waves within a block offset by >=2 chunks
// (~1000 cyc), co-resident blocks by 1; chunks are fully independent so the
// permutation is semantically null. No new regs/LDS/barriers.
__global__ __launch_bounds__(256, 3) void mlp_mfma(
    const unsigned short* __restrict__ Xpad,
    const unsigned short* __restrict__ W0b,
    const unsigned short* __restrict__ W1b,
    const unsigned short* __restrict__ W2b,
    const float* __restrict__ b0, const float* __restrict__ b1,
    const float* __restrict__ b2, float* __restrict__ out)
{
    __shared__ __align__(16) unsigned short xs[37 * 512];        // 37,888 B
    __shared__ __align__(8)  unsigned short yt[256][4];          //  2,048 B (bf16)

    const int tileid = blockIdx.x;
    const int ng     = blockIdx.y;
    const int b      = tileid >> 3;
    const int t0     = (tileid & 7) * 256;
    const int tid    = threadIdx.x;
    const int wave   = tid >> 6;
    const int lane   = tid & 63;
    const int quad   = lane >> 4;
    const int l15    = lane & 15;

    // ---- stage X tile: direct global->LDS DMA, 1 KB per instruction ----
    {
        const char* srcb = (const char*)(Xpad + (size_t)(b * TIN + t0) * XSTRIDE);
        #pragma unroll 1
        for (int i = wave; i < 37; i += 4) {
            __builtin_amdgcn_global_load_lds(
                (const __attribute__((address_space(1))) unsigned int*)(srcb + i * 1024 + lane * 16),
                (__attribute__((address_space(3))) unsigned int*)((char*)xs + i * 1024),
                16, 0, 0);
        }
    }

    // ---- per-wave net: weight fragments (pre-repacked bf16), loaded once ----
    const int n = ng * 4 + wave;
    short8 B0[10][2];
    const unsigned short* wp0 = W0b + (n * H0 + l15) * (NCH * LAG) + quad * 8;
    #pragma unroll
    for (int ks = 0; ks < 10; ++ks) {
        B0[ks][0] = *(const short8*)(wp0 + ks * 32);
        B0[ks][1] = *(const short8*)(wp0 + 16 * (NCH * LAG) + ks * 32);
    }
    short4v A1[2][2];
    #pragma unroll
    for (int of = 0; of < 2; ++of)
        #pragma unroll
        for (int kf = 0; kf < 2; ++kf)
            A1[of][kf] = *(const short4v*)(W1b + (n * H1 + of * 16 + l15) * H0 + kf * 16 + quad * 4);
    short4v A2[2];
    #pragma unroll
    for (int kf = 0; kf < 2; ++kf)
        A2[kf] = *(const short4v*)(W2b + n * H1 + kf * 16 + quad * 4);
    f32x4 b0q[2], b1q[2];
    #pragma unroll
    for (int nf = 0; nf < 2; ++nf) b0q[nf] = *(const f32x4*)(b0 + (size_t)n * H0 + nf * 16 + quad * 4);
    #pragma unroll
    for (int of = 0; of < 2; ++of) b1q[of] = *(const f32x4*)(b1 + (size_t)n * H1 + of * 16 + quad * 4);
    const float b2s = b2[n];

    __syncthreads();   // drains global_load_lds (vmcnt) + weight loads

    const int vmax  = (t0 == 1792) ? 251 : 255;
    const int phase = wave * 2 + ((tileid ^ ng) & 1);   // per-wave desync offset

    #pragma unroll 1
    for (int ci = 0; ci < 8; ++ci) {
        const int chunk = (ci + phase) & 7;

        int rowoff[2];
        #pragma unroll
        for (int mf = 0; mf < 2; ++mf) {
            int i = chunk * 32 + mf * 16 + l15;
            i = i < vmax ? i : vmax;
            rowoff[mf] = i * XSTRIDE + quad * 8;
        }

        // ---- layer 0 (transposed): acc[mf][nf] = C[row=h][col=pos] ----
        f32x4 acc[2][2];
        #pragma unroll
        for (int mf = 0; mf < 2; ++mf) {
            acc[mf][0] = b0q[0];
            acc[mf][1] = b0q[1];
        }
        __builtin_amdgcn_s_setprio(1);
        #pragma unroll
        for (int ks = 0; ks < 10; ++ks) {
            const int xoff = (ks >> 1) * XSTRIDE + (ks & 1) * 32;
            #pragma unroll
            for (int mf = 0; mf < 2; ++mf) {
                short8 Xf = *(const short8*)&xs[rowoff[mf] + xoff];   // B-op: n=pos
                acc[mf][0] = __builtin_amdgcn_mfma_f32_16x16x32_bf16(B0[ks][0], Xf, acc[mf][0], 0, 0, 0);
                acc[mf][1] = __builtin_amdgcn_mfma_f32_16x16x32_bf16(B0[ks][1], Xf, acc[mf][1], 0, 0, 0);
            }
        }
        __builtin_amdgcn_s_setprio(0);

        // ---- layers 1+2: register-only ----
        #pragma unroll
        for (int mf = 0; mf < 2; ++mf) {
            short4v Bh0 = pack4bf_relu(acc[mf][0]);   // h 0..15
            short4v Bh1 = pack4bf_relu(acc[mf][1]);   // h 16..31

            f32x4 D1[2] = { b1q[0], b1q[1] };
            __builtin_amdgcn_s_setprio(1);
            D1[0] = __builtin_amdgcn_mfma_f32_16x16x16bf16_1k(A1[0][0], Bh0, D1[0], 0, 0, 0);
            D1[0] = __builtin_amdgcn_mfma_f32_16x16x16bf16_1k(A1[0][1], Bh1, D1[0], 0, 0, 0);
            D1[1] = __builtin_amdgcn_mfma_f32_16x16x16bf16_1k(A1[1][0], Bh0, D1[1], 0, 0, 0);
            D1[1] = __builtin_amdgcn_mfma_f32_16x16x16bf16_1k(A1[1][1], Bh1, D1[1], 0, 0, 0);
            __builtin_amdgcn_s_setprio(0);

            short4v Bg0 = pack4bf_relu(D1[0]);        // o 0..15
            short4v Bg1 = pack4bf_relu(D1[1]);        // o 16..31

            f32x4 D2 = (f32x4){ b2s, b2s, b2s, b2s };
            __builtin_amdgcn_s_setprio(1);
            D2 = __builtin_amdgcn_mfma_f32_16x16x16bf16_1k(A2[0], Bg0, D2, 0, 0, 0);
            D2 = __builtin_amdgcn_mfma_f32_16x16x16bf16_1k(A2[1], Bg1, D2, 0, 0, 0);
            __builtin_amdgcn_s_setprio(0);

            if (quad == 0)
                yt[chunk * 32 + mf * 16 + l15][wave] = f2bf(D2[0]);
        }
    }
    __syncthreads();

    // ---- coalesced output: bf16 yt -> float4 per thread ----
    int t = t0 + tid;
    if (t < TOUT) {
        ushort4 v = *(const ushort4*)yt[tid];
        float4 o;
        o.x = __uint_as_float((unsigned)v.x << 16);
        o.y = __uint_as_float((unsigned)v.y << 16);
        o.z = __uint_as_float((unsigned)v.z << 16);
        o.w = __uint_as_float((unsigned)v.w << 16);
        *(float4*)&out[((size_t)(b * TOUT + t)) * NCH + ng * 4] = o;
    }
}

extern "C" void kernel_launch(void* const* d_in, const int* in_sizes, int n_in,
                              void* d_out, int out_size, void* d_ws, size_t ws_size,
                              hipStream_t stream)
{
    const float* X  = (const float*)d_in[0];
    const float* W0 = (const float*)d_in[1];
    const float* b0 = (const float*)d_in[2];
    const float* W1 = (const float*)d_in[3];
    const float* b1 = (const float*)d_in[4];
    const float* W2 = (const float*)d_in[5];
    const float* b2 = (const float*)d_in[6];
    float* out = (float*)d_out;

    // ws layout: Xpad 4,718,592 B (+8,192 cushion for tail over-copy), then weights
    unsigned short* Xpad = (unsigned short*)d_ws;
    unsigned short* W0b  = (unsigned short*)((char*)d_ws + 4726784);   // 1,310,720 B
    unsigned short* W1b  = (unsigned short*)((char*)d_ws + 6037504);   //   131,072 B
    unsigned short* W2b  = (unsigned short*)((char*)d_ws + 6168576);   //     4,096 B

    prep_all<<<1057, 256, 0, stream>>>(X, Xpad, W0, W0b, W1, W1b, W2, W2b);
    mlp_mfma<<<dim3(128, 16), 256, 0, stream>>>(Xpad, W0b, W1b, W2b, b0, b1, b2, out);
}